// Round 4
// baseline (40054.291 us; speedup 1.0000x reference)
//
#include <hip/hip_runtime.h>
#include <math.h>

// Problem constants
#define B_ 256
#define S_ 128
#define F_ 128
#define H_ 512
#define A_ 512
#define C_ 128

#define DOT4(va, vb) ((va).x*(vb).x + (va).y*(vb).y + (va).z*(vb).z + (va).w*(vb).w)

// ---------------------------------------------------------------------------
// Pack GRU weights: rows = [x-part (K1) | h-part (K2)] -> out[(K1+K2)/4][N] f4
// out[kq][jg] = W[jg][4kq..4kq+3]  (jg in [0,N))
// ---------------------------------------------------------------------------
__global__ __launch_bounds__(256)
void prep_wt(const float* __restrict__ Wx, int K1,
             const float* __restrict__ Wh, int K2,
             float4* __restrict__ out, int N, int total)
{
    int id = blockIdx.x * 256 + threadIdx.x;
    if (id >= total) return;
    int kq = id / N, jg = id - kq * N;
    int k4 = kq * 4;
    float4 r;
    if (k4 < K1) {
        const float* s = Wx + (size_t)jg * K1 + k4;
        r = make_float4(s[0], s[1], s[2], s[3]);
    } else {
        const float* s = Wh + (size_t)jg * K2 + (k4 - K1);
        r = make_float4(s[0], s[1], s[2], s[3]);
    }
    out[id] = r;
}

// ---------------------------------------------------------------------------
// Encoder: 64 blocks, block owns batch rows b0..b0+3 for all 128 steps.
// Thread owns hidden units j0=tid, j1=tid+256 (all 3 gates).
// WT4 = packed [160][1536]: rows 0..31 = Wih (k=F), rows 32..159 = Whh (k=H).
// ---------------------------------------------------------------------------
__global__ __launch_bounds__(256)
void enc_kernel(const float* __restrict__ x,
                const float4* __restrict__ WT4,
                const float* __restrict__ bih, const float* __restrict__ bhh,
                float* __restrict__ enc_out, float* __restrict__ hT)
{
    __shared__ float4 hb4[2][4][128];
    const int tid = threadIdx.x;
    const int b0 = blockIdx.x * 4;
    const int j0 = tid, j1 = tid + 256;

    {
        float4 z = make_float4(0.f, 0.f, 0.f, 0.f);
#pragma unroll
        for (int u = 0; u < 2; ++u) {
            int idx = tid + u * 256;
            hb4[0][idx >> 7][idx & 127] = z;
        }
    }
    const float br0 = bih[j0] + bhh[j0];
    const float br1 = bih[j1] + bhh[j1];
    const float bz0 = bih[H_ + j0] + bhh[H_ + j0];
    const float bz1 = bih[H_ + j1] + bhh[H_ + j1];
    const float bi0 = bih[2 * H_ + j0], bi1 = bih[2 * H_ + j1];
    const float bh0 = bhh[2 * H_ + j0], bh1 = bhh[2 * H_ + j1];
    __syncthreads();

    int cur = 0;
    for (int t = 0; t < S_; ++t) {
        const int nxt = cur ^ 1;
        float acc[4][8];
#pragma unroll
        for (int b = 0; b < 4; ++b)
#pragma unroll
            for (int p = 0; p < 8; ++p) acc[b][p] = 0.f;

        const float4* xr[4];
#pragma unroll
        for (int b = 0; b < 4; ++b)
            xr[b] = (const float4*)(x + ((size_t)(b0 + b) * S_ + t) * F_);

        // ---- x part (32 kq) -> acc slots {0,1,2,3,4,5} ----
#pragma unroll 2
        for (int kq = 0; kq < 32; ++kq) {
            const float4* wr = WT4 + (size_t)kq * 1536;
            float4 w0 = wr[j0], w1 = wr[j1];
            float4 w2v = wr[512 + j0], w3 = wr[512 + j1];
            float4 w4 = wr[1024 + j0], w5 = wr[1024 + j1];
#pragma unroll
            for (int b = 0; b < 4; ++b) {
                float4 a = xr[b][kq];
                acc[b][0] += DOT4(a, w0);  acc[b][1] += DOT4(a, w1);
                acc[b][2] += DOT4(a, w2v); acc[b][3] += DOT4(a, w3);
                acc[b][4] += DOT4(a, w4);  acc[b][5] += DOT4(a, w5);
            }
        }
        // ---- h part (128 kq) -> acc slots {0,1,2,3,6,7} ----
#pragma unroll 2
        for (int kq = 0; kq < 128; ++kq) {
            const float4* wr = WT4 + (size_t)(32 + kq) * 1536;
            float4 w0 = wr[j0], w1 = wr[j1];
            float4 w2v = wr[512 + j0], w3 = wr[512 + j1];
            float4 w4 = wr[1024 + j0], w5 = wr[1024 + j1];
#pragma unroll
            for (int b = 0; b < 4; ++b) {
                float4 a = hb4[cur][b][kq];
                acc[b][0] += DOT4(a, w0);  acc[b][1] += DOT4(a, w1);
                acc[b][2] += DOT4(a, w2v); acc[b][3] += DOT4(a, w3);
                acc[b][6] += DOT4(a, w4);  acc[b][7] += DOT4(a, w5);
            }
        }
        // ---- gates ----
#pragma unroll
        for (int b = 0; b < 4; ++b) {
            float r0 = 1.f / (1.f + expf(-(acc[b][0] + br0)));
            float r1 = 1.f / (1.f + expf(-(acc[b][1] + br1)));
            float z0 = 1.f / (1.f + expf(-(acc[b][2] + bz0)));
            float z1 = 1.f / (1.f + expf(-(acc[b][3] + bz1)));
            float n0 = tanhf(acc[b][4] + bi0 + r0 * (acc[b][6] + bh0));
            float n1 = tanhf(acc[b][5] + bi1 + r1 * (acc[b][7] + bh1));
            const float* hc = (const float*)&hb4[cur][b][0];
            float h0v = (1.f - z0) * n0 + z0 * hc[j0];
            float h1v = (1.f - z1) * n1 + z1 * hc[j1];
            float* hn = (float*)&hb4[nxt][b][0];
            hn[j0] = h0v; hn[j1] = h1v;
            float* eo = enc_out + ((size_t)(b0 + b) * S_ + t) * H_;
            eo[j0] = h0v; eo[j1] = h1v;
        }
        __syncthreads();
        cur = nxt;
    }
    // final hidden state
#pragma unroll
    for (int b = 0; b < 4; ++b) {
        const float* hc = (const float*)&hb4[cur][b][0];
        float* o = hT + (size_t)(b0 + b) * H_;
        o[j0] = hc[j0]; o[j1] = hc[j1];
    }
}

// ---------------------------------------------------------------------------
// Decoder: 64 blocks, block owns b0..b0+3 for all 128 steps.
// Per step: GRU (as encoder, x row gathered by prev pred) -> w2 -> attention.
// ---------------------------------------------------------------------------
__global__ __launch_bounds__(256)
void dec_kernel(const float* __restrict__ x, const int* __restrict__ y,
                const float4* __restrict__ WT4,   // [160][1536]
                const float* __restrict__ bih, const float* __restrict__ bhh,
                const float4* __restrict__ w2T4,  // [128][512]
                const float* __restrict__ v,
                const float* __restrict__ proj,   // [(b*128+s)][512]
                const float* __restrict__ hT,
                float* __restrict__ nlogp, float* __restrict__ preds)
{
    __shared__ float4 hb4[2][4][128];
    __shared__ float4 hw2L4[4][128];
    __shared__ float4 vL4[128];
    __shared__ int predL[4];

    const int tid = threadIdx.x;
    const int b0 = blockIdx.x * 4;
    const int j0 = tid, j1 = tid + 256;
    const int wv = tid >> 6, ln = tid & 63;

#pragma unroll
    for (int u = 0; u < 2; ++u) {
        int idx = tid + u * 256;
        hb4[0][idx >> 7][idx & 127] =
            ((const float4*)hT)[(size_t)(b0 + (idx >> 7)) * 128 + (idx & 127)];
    }
    if (tid < 128) vL4[tid] = ((const float4*)v)[tid];

    const float br0 = bih[j0] + bhh[j0];
    const float br1 = bih[j1] + bhh[j1];
    const float bz0 = bih[H_ + j0] + bhh[H_ + j0];
    const float bz1 = bih[H_ + j1] + bhh[H_ + j1];
    const float bi0 = bih[2 * H_ + j0], bi1 = bih[2 * H_ + j1];
    const float bh0 = bhh[2 * H_ + j0], bh1 = bhh[2 * H_ + j1];
    __syncthreads();

    int cur = 0;
    for (int i = 0; i < C_; ++i) {
        const int nxt = cur ^ 1;
        float acc[4][8];
#pragma unroll
        for (int b = 0; b < 4; ++b)
#pragma unroll
            for (int p = 0; p < 8; ++p) acc[b][p] = 0.f;

        if (i > 0) {
            const float4* xr[4];
#pragma unroll
            for (int b = 0; b < 4; ++b)
                xr[b] = (const float4*)(x + ((size_t)(b0 + b) * S_ + predL[b]) * F_);
#pragma unroll 2
            for (int kq = 0; kq < 32; ++kq) {
                const float4* wr = WT4 + (size_t)kq * 1536;
                float4 w0 = wr[j0], w1 = wr[j1];
                float4 w2v = wr[512 + j0], w3 = wr[512 + j1];
                float4 w4 = wr[1024 + j0], w5 = wr[1024 + j1];
#pragma unroll
                for (int b = 0; b < 4; ++b) {
                    float4 a = xr[b][kq];
                    acc[b][0] += DOT4(a, w0);  acc[b][1] += DOT4(a, w1);
                    acc[b][2] += DOT4(a, w2v); acc[b][3] += DOT4(a, w3);
                    acc[b][4] += DOT4(a, w4);  acc[b][5] += DOT4(a, w5);
                }
            }
        }
#pragma unroll 2
        for (int kq = 0; kq < 128; ++kq) {
            const float4* wr = WT4 + (size_t)(32 + kq) * 1536;
            float4 w0 = wr[j0], w1 = wr[j1];
            float4 w2v = wr[512 + j0], w3 = wr[512 + j1];
            float4 w4 = wr[1024 + j0], w5 = wr[1024 + j1];
#pragma unroll
            for (int b = 0; b < 4; ++b) {
                float4 a = hb4[cur][b][kq];
                acc[b][0] += DOT4(a, w0);  acc[b][1] += DOT4(a, w1);
                acc[b][2] += DOT4(a, w2v); acc[b][3] += DOT4(a, w3);
                acc[b][6] += DOT4(a, w4);  acc[b][7] += DOT4(a, w5);
            }
        }
#pragma unroll
        for (int b = 0; b < 4; ++b) {
            float r0 = 1.f / (1.f + expf(-(acc[b][0] + br0)));
            float r1 = 1.f / (1.f + expf(-(acc[b][1] + br1)));
            float z0 = 1.f / (1.f + expf(-(acc[b][2] + bz0)));
            float z1 = 1.f / (1.f + expf(-(acc[b][3] + bz1)));
            float n0 = tanhf(acc[b][4] + bi0 + r0 * (acc[b][6] + bh0));
            float n1 = tanhf(acc[b][5] + bi1 + r1 * (acc[b][7] + bh1));
            const float* hc = (const float*)&hb4[cur][b][0];
            float h0v = (1.f - z0) * n0 + z0 * hc[j0];
            float h1v = (1.f - z1) * n1 + z1 * hc[j1];
            float* hn = (float*)&hb4[nxt][b][0];
            hn[j0] = h0v; hn[j1] = h1v;
        }
        __syncthreads();

        // ---- phase 2: hw2[b][a] = h_new[b] . w2[a] ----
        {
            const int bp = wv & 1, ah = wv >> 1;
            const int a_base = ah * 256 + ln;
            float a2[2][4];
#pragma unroll
            for (int q = 0; q < 2; ++q)
#pragma unroll
                for (int m = 0; m < 4; ++m) a2[q][m] = 0.f;
#pragma unroll 2
            for (int kq = 0; kq < 128; ++kq) {
                float4 h0 = hb4[nxt][bp * 2 + 0][kq];
                float4 h1 = hb4[nxt][bp * 2 + 1][kq];
                const float4* wr = w2T4 + (size_t)kq * 512 + a_base;
                float4 wA = wr[0], wB = wr[64], wC = wr[128], wD = wr[192];
                a2[0][0] += DOT4(h0, wA); a2[0][1] += DOT4(h0, wB);
                a2[0][2] += DOT4(h0, wC); a2[0][3] += DOT4(h0, wD);
                a2[1][0] += DOT4(h1, wA); a2[1][1] += DOT4(h1, wB);
                a2[1][2] += DOT4(h1, wC); a2[1][3] += DOT4(h1, wD);
            }
            float* hwf = (float*)hw2L4;
#pragma unroll
            for (int m = 0; m < 4; ++m) {
                hwf[(bp * 2 + 0) * 512 + a_base + m * 64] = a2[0][m];
                hwf[(bp * 2 + 1) * 512 + a_base + m * 64] = a2[1][m];
            }
        }
        __syncthreads();

        // ---- phase 3: attention + softmax + argmax + loss (wave wv = b) ----
        {
            const int gb = b0 + wv;
            const float* pr0 = proj + ((size_t)gb * S_ + ln) * A_;
            const float* pr1 = pr0 + (size_t)64 * A_;
            float sc0 = 0.f, sc1 = 0.f;
#pragma unroll 4
            for (int aq = 0; aq < 128; ++aq) {
                float4 hv = hw2L4[wv][aq];
                float4 vv = vL4[aq];
                float4 q0 = ((const float4*)pr0)[aq];
                float4 q1 = ((const float4*)pr1)[aq];
                sc0 += fmaxf(q0.x + hv.x, 0.f) * vv.x
                     + fmaxf(q0.y + hv.y, 0.f) * vv.y
                     + fmaxf(q0.z + hv.z, 0.f) * vv.z
                     + fmaxf(q0.w + hv.w, 0.f) * vv.w;
                sc1 += fmaxf(q1.x + hv.x, 0.f) * vv.x
                     + fmaxf(q1.y + hv.y, 0.f) * vv.y
                     + fmaxf(q1.z + hv.z, 0.f) * vv.z
                     + fmaxf(q1.w + hv.w, 0.f) * vv.w;
            }
            float m = fmaxf(sc0, sc1);
#pragma unroll
            for (int off = 32; off; off >>= 1) m = fmaxf(m, __shfl_xor(m, off));
            float e0 = expf(sc0 - m), e1 = expf(sc1 - m);
            float se = e0 + e1;
#pragma unroll
            for (int off = 32; off; off >>= 1) se += __shfl_xor(se, off);
            float p0 = e0 / se, p1 = e1 / se;
            float pm = fmaxf(p0, p1);
#pragma unroll
            for (int off = 32; off; off >>= 1) pm = fmaxf(pm, __shfl_xor(pm, off));
            float t0 = expf(p0 - pm), t1 = expf(p1 - pm);
            float T = t0 + t1;
#pragma unroll
            for (int off = 32; off; off >>= 1) T += __shfl_xor(T, off);
            int yy = y[(size_t)gb * C_ + i];
            float py = ((ln == yy) ? p0 : 0.f) + ((ln + 64 == yy) ? p1 : 0.f);
#pragma unroll
            for (int off = 32; off; off >>= 1) py += __shfl_xor(py, off);
            float bv = p0; int bi2 = ln;
            if (p1 > bv) { bv = p1; bi2 = ln + 64; }
#pragma unroll
            for (int off = 32; off; off >>= 1) {
                float ov = __shfl_xor(bv, off);
                int oi = __shfl_xor(bi2, off);
                if (ov > bv || (ov == bv && oi < bi2)) { bv = ov; bi2 = oi; }
            }
            if (ln == 0) {
                predL[wv] = bi2;
                nlogp[(size_t)i * B_ + gb] = -(py - pm - logf(T));
                preds[(size_t)gb * C_ + i] = (float)bi2;
            }
        }
        __syncthreads();
        cur = nxt;
    }
}

// ---------------------------------------------------------------------------
// C[m][n] = sum_k A[m*K+k] * Bw[n*K+k]
// ---------------------------------------------------------------------------
template<int BM, int BN, int TM, int TN>
__global__ __launch_bounds__(256)
void gemm_nt(const float* __restrict__ A, const float* __restrict__ Bw,
             float* __restrict__ C, int M, int N, int K)
{
    constexpr int KC = 32;
    constexpr int TX = BN / TN;
    constexpr int TY = BM / TM;
    __shared__ float4 sA[(KC / 4) * BM];
    __shared__ float4 sB[(KC / 4) * BN];

    const int tid = threadIdx.x;
    const int tx = tid % TX, ty = tid / TX;
    const int m0 = blockIdx.y * BM, n0 = blockIdx.x * BN;

    float acc[TM][TN];
#pragma unroll
    for (int i = 0; i < TM; i++)
#pragma unroll
        for (int jj = 0; jj < TN; jj++) acc[i][jj] = 0.f;

    for (int kc = 0; kc < K; kc += KC) {
        for (int idx = tid; idx < BM * 8; idx += 256) {
            int r = idx >> 3, kv = idx & 7;
            sA[kv * BM + r] = *(const float4*)(A + (size_t)(m0 + r) * K + kc + kv * 4);
        }
        for (int idx = tid; idx < BN * 8; idx += 256) {
            int r = idx >> 3, kv = idx & 7;
            sB[kv * BN + r] = *(const float4*)(Bw + (size_t)(n0 + r) * K + kc + kv * 4);
        }
        __syncthreads();
#pragma unroll
        for (int kk = 0; kk < KC / 4; ++kk) {
            float4 af[TM], bf[TN];
#pragma unroll
            for (int i = 0; i < TM; i++) af[i] = sA[kk * BM + ty + i * TY];
#pragma unroll
            for (int jj = 0; jj < TN; jj++) bf[jj] = sB[kk * BN + tx + jj * TX];
#pragma unroll
            for (int i = 0; i < TM; i++)
#pragma unroll
                for (int jj = 0; jj < TN; jj++)
                    acc[i][jj] += DOT4(af[i], bf[jj]);
        }
        __syncthreads();
    }
#pragma unroll
    for (int i = 0; i < TM; i++)
#pragma unroll
        for (int jj = 0; jj < TN; jj++)
            C[(size_t)(m0 + ty + i * TY) * N + n0 + tx + jj * TX] = acc[i][jj];
}

__global__ void final_loss(const float* __restrict__ nlogp, float* __restrict__ out)
{
    __shared__ float part[C_];
    const int i = threadIdx.x; // 128
    float s = 0.f;
    for (int b = 0; b < B_; ++b) s += nlogp[(size_t)i * B_ + b];
    part[i] = s / (float)B_;
    __syncthreads();
    if (i == 0) {
        float t = 0.f;
        for (int k = 0; k < C_; ++k) t += part[k];
        out[0] = t / (float)B_ / (float)C_;
    }
}

extern "C" void kernel_launch(void* const* d_in, const int* in_sizes, int n_in,
                              void* d_out, int out_size, void* d_ws, size_t ws_size,
                              hipStream_t stream)
{
    (void)in_sizes; (void)n_in; (void)out_size; (void)ws_size;
    const float* x    = (const float*)d_in[0];
    const int*   y    = (const int*)d_in[1];
    const float* eWih = (const float*)d_in[2];
    const float* eWhh = (const float*)d_in[3];
    const float* ebih = (const float*)d_in[4];
    const float* ebhh = (const float*)d_in[5];
    const float* dWih = (const float*)d_in[6];
    const float* dWhh = (const float*)d_in[7];
    const float* dbih = (const float*)d_in[8];
    const float* dbhh = (const float*)d_in[9];
    const float* w1   = (const float*)d_in[10];
    const float* w2   = (const float*)d_in[11];
    const float* v    = (const float*)d_in[12];
    float* out = (float*)d_out;

    float* ws = (float*)d_ws;
    float* enc_out = ws;                          // 16777216 floats (64 MiB)
    float* proj    = ws + 16777216;               // 16777216 floats (64 MiB)
    float* hT      = ws + 2 * 16777216;           // 131072
    float* nlogp   = hT + 131072;                 // 32768
    // aliased regions:
    float4* WT4e = (float4*)proj;                 // 983040 floats, dead after enc
    float4* WT4d = (float4*)enc_out;              // 983040 floats, written post-proj
    float4* w2T4 = (float4*)(enc_out + 983040);   // 262144 floats

    // 1. pack encoder weights (into proj region, proj not yet written)
    prep_wt<<<dim3(960), 256, 0, stream>>>(eWih, F_, eWhh, H_, WT4e, 1536, 160 * 1536);

    // 2. encoder (reads WT4e, writes enc_out + hT)
    enc_kernel<<<dim3(64), 256, 0, stream>>>(x, WT4e, ebih, ebhh, enc_out, hT);

    // 3. proj = enc_out @ w1^T  (overwrites WT4e region - enc done)
    gemm_nt<64, 64, 4, 4><<<dim3(A_ / 64, (B_ * S_) / 64), 256, 0, stream>>>(
        enc_out, w1, proj, B_ * S_, A_, H_);

    // 4. pack decoder weights (into enc_out region - proj done reading it)
    prep_wt<<<dim3(960), 256, 0, stream>>>(dWih, F_, dWhh, H_, WT4d, 1536, 160 * 1536);
    prep_wt<<<dim3(256), 256, 0, stream>>>(nullptr, 0, w2, H_, w2T4, 512, 128 * 512);

    // 5. decoder
    dec_kernel<<<dim3(64), 256, 0, stream>>>(x, y, WT4d, dbih, dbhh, w2T4, v,
                                             proj, hT, nlogp, out);

    // 6. loss
    final_loss<<<dim3(1), 128, 0, stream>>>(nlogp, out + (size_t)B_ * C_);
}

// Round 5
// 9793.333 us; speedup vs baseline: 4.0900x; 4.0900x over previous
//
#include <hip/hip_runtime.h>
#include <math.h>

// Problem constants
#define B_ 256
#define S_ 128
#define F_ 128
#define H_ 512
#define A_ 512
#define C_ 128

// ---------------------------------------------------------------------------
// xT[t][f][b] = x[b][t][f]
// ---------------------------------------------------------------------------
__global__ __launch_bounds__(256)
void transpose_x(const float* __restrict__ x, float* __restrict__ xT)
{
    const int t = blockIdx.x >> 2;
    const int f0 = (blockIdx.x & 3) * 32;
    const int b = threadIdx.x;
#pragma unroll 4
    for (int ff = 0; ff < 32; ++ff) {
        int f = f0 + ff;
        xT[(size_t)t * (F_ * B_) + (size_t)f * B_ + b] =
            x[(size_t)b * (S_ * F_) + (size_t)t * F_ + f];
    }
}

// ---------------------------------------------------------------------------
// W6[up][k][6]: up owns units u0=2up,u0+1. g order: r(u0),r(u1),z(u0),z(u1),n(u0),n(u1)
// k<128 -> Wih (K=F), k>=128 -> Whh (K=H)
// ---------------------------------------------------------------------------
__global__ __launch_bounds__(256)
void prep_w6(const float* __restrict__ Wih, const float* __restrict__ Whh,
             float* __restrict__ W6)
{
    int id = blockIdx.x * 256 + threadIdx.x;
    if (id >= 256 * 640 * 6) return;
    int up = id / 3840;
    int rem = id - up * 3840;
    int k = rem / 6, g = rem - k * 6;
    int row = (g >> 1) * H_ + up * 2 + (g & 1);
    float val;
    if (k < F_) val = Wih[(size_t)row * F_ + k];
    else        val = Whh[(size_t)row * H_ + (k - F_)];
    W6[id] = val;
}

// w2pk[ap][k][2] = w2[2ap+g][k]; also zero dec_inT
__global__ __launch_bounds__(256)
void prep_w2pk(const float* __restrict__ w2, float* __restrict__ w2pk,
               float* __restrict__ dec_inT)
{
    int id = blockIdx.x * 256 + threadIdx.x;
    if (id < 256 * 512 * 2) {
        int ap = id / 1024;
        int rem = id - ap * 1024;
        int k = rem >> 1, g = rem & 1;
        w2pk[id] = w2[(size_t)(ap * 2 + g) * H_ + k];
    }
    if (id < F_ * B_) dec_inT[id] = 0.f;
}

// bias4[u] = {bih[u]+bhh[u], bih[H+u]+bhh[H+u], bih[2H+u], bhh[2H+u]}; zero h0T
__global__ __launch_bounds__(256)
void prep_bias(const float* __restrict__ ebih, const float* __restrict__ ebhh,
               const float* __restrict__ dbih, const float* __restrict__ dbhh,
               float* __restrict__ bias4e, float* __restrict__ bias4d,
               float* __restrict__ h0T)
{
    int id = blockIdx.x * 256 + threadIdx.x;
    if (id < H_ * B_) h0T[id] = 0.f;
    if (id < H_) {
        bias4e[id * 4 + 0] = ebih[id] + ebhh[id];
        bias4e[id * 4 + 1] = ebih[H_ + id] + ebhh[H_ + id];
        bias4e[id * 4 + 2] = ebih[2 * H_ + id];
        bias4e[id * 4 + 3] = ebhh[2 * H_ + id];
        bias4d[id * 4 + 0] = dbih[id] + dbhh[id];
        bias4d[id * 4 + 1] = dbih[H_ + id] + dbhh[H_ + id];
        bias4d[id * 4 + 2] = dbih[2 * H_ + id];
        bias4d[id * 4 + 3] = dbhh[2 * H_ + id];
    }
}

// ---------------------------------------------------------------------------
// accumulate nk k-values from k-major src into acc[0..3] and acc[NH],acc[NH+1]
// W6k: [k][6] aligned with src's k range. Double-buffered 8-chunks.
// ---------------------------------------------------------------------------
template<int NH>
__device__ __forceinline__ void acc_range(const float* __restrict__ src,
                                          const float* __restrict__ W6k,
                                          int nk, int b, float* __restrict__ acc)
{
    float a0[8], a1[8];
#pragma unroll
    for (int j = 0; j < 8; ++j) a0[j] = src[(size_t)j * B_ + b];
    for (int kc = 0; kc < nk; kc += 8) {
        if (kc + 8 < nk) {
#pragma unroll
            for (int j = 0; j < 8; ++j) a1[j] = src[(size_t)(kc + 8 + j) * B_ + b];
        }
        const float* Wr = W6k + (size_t)kc * 6;
#pragma unroll
        for (int j = 0; j < 8; ++j) {
            float av = a0[j];
            acc[0]      = fmaf(av, Wr[j * 6 + 0], acc[0]);
            acc[1]      = fmaf(av, Wr[j * 6 + 1], acc[1]);
            acc[2]      = fmaf(av, Wr[j * 6 + 2], acc[2]);
            acc[3]      = fmaf(av, Wr[j * 6 + 3], acc[3]);
            acc[NH]     = fmaf(av, Wr[j * 6 + 4], acc[NH]);
            acc[NH + 1] = fmaf(av, Wr[j * 6 + 5], acc[NH + 1]);
        }
#pragma unroll
        for (int j = 0; j < 8; ++j) a0[j] = a1[j];
    }
}

// ---------------------------------------------------------------------------
// One GRU step. 256 blocks (unit-pair each), 512 threads = 8 waves:
// wave = (kw: k-half) x (bg: 64-batch group). k-major activations, uniform weights.
// acc slots: 0,1=r(u0,u1); 2,3=z; 4,5=n x-part; 6,7=n h-part.
// ---------------------------------------------------------------------------
__global__ __launch_bounds__(512)
void gru_step(const float* __restrict__ inT,    // [F_][B_] x-part (k-major)
              const float* __restrict__ hinT,   // [H_][B_]
              const float* __restrict__ W6,     // [256][640][6]
              const float* __restrict__ bias4,  // [512][4]
              float* __restrict__ houtT)        // [H_][B_]
{
    __shared__ float accL[256][6];
    const int tid = threadIdx.x;
    const int lane = tid & 63;
    const int w = tid >> 6;
    const int bg = w & 3;
    const int kw = w >> 2;
    const int b = bg * 64 + lane;
    const int up = blockIdx.x;
    const float* Wb = W6 + (size_t)up * (640 * 6);

    float acc[8];
#pragma unroll
    for (int g = 0; g < 8; ++g) acc[g] = 0.f;

    if (kw == 0) {
        acc_range<4>(inT, Wb, F_, b, acc);                       // x: k 0..127
        acc_range<6>(hinT, Wb + F_ * 6, 192, b, acc);            // h: k 0..191
    } else {
        acc_range<6>(hinT + (size_t)192 * B_, Wb + 320 * 6, 320, b, acc); // h: 192..511
    }

    if (kw == 1) {
        const int li = tid & 255;
        accL[li][0] = acc[0]; accL[li][1] = acc[1];
        accL[li][2] = acc[2]; accL[li][3] = acc[3];
        accL[li][4] = acc[6]; accL[li][5] = acc[7];
    }
    __syncthreads();
    if (kw == 0) {
        const int u0 = up * 2, u1 = u0 + 1;
        float4 bb0 = *(const float4*)(bias4 + u0 * 4);
        float4 bb1 = *(const float4*)(bias4 + u1 * 4);
        float rr0 = 1.f / (1.f + expf(-(acc[0] + accL[tid][0] + bb0.x)));
        float rr1 = 1.f / (1.f + expf(-(acc[1] + accL[tid][1] + bb1.x)));
        float zz0 = 1.f / (1.f + expf(-(acc[2] + accL[tid][2] + bb0.y)));
        float zz1 = 1.f / (1.f + expf(-(acc[3] + accL[tid][3] + bb1.y)));
        float hn0 = acc[6] + accL[tid][4] + bb0.w;
        float hn1 = acc[7] + accL[tid][5] + bb1.w;
        float nn0 = tanhf(acc[4] + bb0.z + rr0 * hn0);
        float nn1 = tanhf(acc[5] + bb1.z + rr1 * hn1);
        float ho0 = hinT[(size_t)u0 * B_ + b];
        float ho1 = hinT[(size_t)u1 * B_ + b];
        houtT[(size_t)u0 * B_ + b] = (1.f - zz0) * nn0 + zz0 * ho0;
        houtT[(size_t)u1 * B_ + b] = (1.f - zz1) * nn1 + zz1 * ho1;
    }
}

// ---------------------------------------------------------------------------
// hw2[b][a] for a-pair per block. Same structure as gru_step.
// ---------------------------------------------------------------------------
__global__ __launch_bounds__(512)
void w2_step(const float* __restrict__ hT, const float* __restrict__ w2pk,
             float* __restrict__ hw2)
{
    __shared__ float accL[256][2];
    const int tid = threadIdx.x;
    const int lane = tid & 63;
    const int w = tid >> 6;
    const int bg = w & 3;
    const int kw = w >> 2;
    const int b = bg * 64 + lane;
    const int ap = blockIdx.x;
    const float* W = w2pk + (size_t)ap * 1024 + (size_t)kw * 512;
    const float* src = hT + (size_t)kw * 256 * B_;

    float acc0 = 0.f, acc1 = 0.f;
    float a0[8], a1[8];
#pragma unroll
    for (int j = 0; j < 8; ++j) a0[j] = src[(size_t)j * B_ + b];
    for (int kc = 0; kc < 256; kc += 8) {
        if (kc + 8 < 256) {
#pragma unroll
            for (int j = 0; j < 8; ++j) a1[j] = src[(size_t)(kc + 8 + j) * B_ + b];
        }
        const float* Wr = W + (size_t)kc * 2;
#pragma unroll
        for (int j = 0; j < 8; ++j) {
            acc0 = fmaf(a0[j], Wr[j * 2 + 0], acc0);
            acc1 = fmaf(a0[j], Wr[j * 2 + 1], acc1);
        }
#pragma unroll
        for (int j = 0; j < 8; ++j) a0[j] = a1[j];
    }
    if (kw == 1) { accL[tid & 255][0] = acc0; accL[tid & 255][1] = acc1; }
    __syncthreads();
    if (kw == 0) {
        hw2[(size_t)b * A_ + ap * 2 + 0] = acc0 + accL[tid][0];
        hw2[(size_t)b * A_ + ap * 2 + 1] = acc1 + accL[tid][1];
    }
}

// ---------------------------------------------------------------------------
// Attention + softmax + argmax + loss + transposed gather. Block = batch b.
// ---------------------------------------------------------------------------
__global__ __launch_bounds__(256)
void attn_step(const float* __restrict__ ep, const float* __restrict__ hw2,
               const float* __restrict__ v, const int* __restrict__ y,
               int step, const float* __restrict__ x,
               float* __restrict__ dec_inT, float* __restrict__ nlogp,
               float* __restrict__ preds_out)
{
    const int b = blockIdx.x;
    const int tid = threadIdx.x;
    __shared__ float sScore[S_], sProb[S_];
    __shared__ int sPred;
    const int wv = tid >> 6, ln = tid & 63;

    float4 q0 = *(const float4*)(hw2 + (size_t)b * A_ + ln * 8);
    float4 q1 = *(const float4*)(hw2 + (size_t)b * A_ + ln * 8 + 4);
    float4 v0r = *(const float4*)(v + ln * 8);
    float4 v1r = *(const float4*)(v + ln * 8 + 4);

    const float* epb = ep + (size_t)b * S_ * A_;
    for (int si = 0; si < S_ / 4; ++si) {
        int s = si * 4 + wv;
        const float* row = epb + (size_t)s * A_ + ln * 8;
        float4 p0 = *(const float4*)(row);
        float4 p1 = *(const float4*)(row + 4);
        float acc = fmaxf(p0.x + q0.x, 0.f) * v0r.x
                  + fmaxf(p0.y + q0.y, 0.f) * v0r.y
                  + fmaxf(p0.z + q0.z, 0.f) * v0r.z
                  + fmaxf(p0.w + q0.w, 0.f) * v0r.w
                  + fmaxf(p1.x + q1.x, 0.f) * v1r.x
                  + fmaxf(p1.y + q1.y, 0.f) * v1r.y
                  + fmaxf(p1.z + q1.z, 0.f) * v1r.z
                  + fmaxf(p1.w + q1.w, 0.f) * v1r.w;
#pragma unroll
        for (int off = 32; off; off >>= 1) acc += __shfl_down(acc, off);
        if (ln == 0) sScore[s] = acc;
    }
    __syncthreads();

    if (tid < 64) {
        float s0v = sScore[tid], s1v = sScore[tid + 64];
        float m = fmaxf(s0v, s1v);
#pragma unroll
        for (int off = 32; off; off >>= 1) m = fmaxf(m, __shfl_xor(m, off));
        float e0 = expf(s0v - m), e1 = expf(s1v - m);
        float se = e0 + e1;
#pragma unroll
        for (int off = 32; off; off >>= 1) se += __shfl_xor(se, off);
        float p0 = e0 / se, p1 = e1 / se;
        sProb[tid] = p0; sProb[tid + 64] = p1;
        float pm = fmaxf(p0, p1);
#pragma unroll
        for (int off = 32; off; off >>= 1) pm = fmaxf(pm, __shfl_xor(pm, off));
        float t0 = expf(p0 - pm), t1 = expf(p1 - pm);
        float T = t0 + t1;
#pragma unroll
        for (int off = 32; off; off >>= 1) T += __shfl_xor(T, off);
        float bv = p0; int bi2 = tid;
        if (p1 > bv) { bv = p1; bi2 = tid + 64; }
#pragma unroll
        for (int off = 32; off; off >>= 1) {
            float ov = __shfl_xor(bv, off);
            int oi = __shfl_xor(bi2, off);
            if (ov > bv || (ov == bv && oi < bi2)) { bv = ov; bi2 = oi; }
        }
        if (tid == 0) {
            sPred = bi2;
            int yy = y[(size_t)b * C_ + step];
            float py = sProb[yy];
            nlogp[(size_t)step * B_ + b] = -(py - pm - logf(T));
            preds_out[(size_t)b * C_ + step] = (float)bi2;
        }
    }
    __syncthreads();

    const int pred = sPred;
    if (tid < F_) {
        dec_inT[(size_t)tid * B_ + b] = x[((size_t)b * S_ + pred) * F_ + tid];
    }
}

// ---------------------------------------------------------------------------
// proj[b][s][a] = sum_j encT[s][j][b] * w1[a][j]   (TN GEMM, 128x128 tiles)
// grid (4 a-tiles, 2 b-tiles, 128 s)
// ---------------------------------------------------------------------------
__global__ __launch_bounds__(256)
void proj_gemm(const float* __restrict__ encT, const float* __restrict__ w1,
               float* __restrict__ proj)
{
    __shared__ float sA[32][128];
    __shared__ float sB[32][128];
    const int tid = threadIdx.x;
    const int s = blockIdx.z;
    const int b0 = blockIdx.y * 128;
    const int a0 = blockIdx.x * 128;
    const int tx = tid & 15, ty = tid >> 4;

    float acc[8][8];
#pragma unroll
    for (int i = 0; i < 8; ++i)
#pragma unroll
        for (int j = 0; j < 8; ++j) acc[i][j] = 0.f;

    const float* Abase = encT + (size_t)s * (H_ * B_) + b0;
    for (int kc = 0; kc < H_; kc += 32) {
#pragma unroll
        for (int p = 0; p < 16; ++p) {
            int idx = tid + p * 256;
            int kj = idx >> 7, bb = idx & 127;
            sA[kj][bb] = Abase[(size_t)(kc + kj) * B_ + bb];
        }
#pragma unroll
        for (int p = 0; p < 16; ++p) {
            int idx = tid + p * 256;
            int aa = idx >> 5, kj = idx & 31;
            sB[kj][aa] = w1[(size_t)(a0 + aa) * H_ + kc + kj];
        }
        __syncthreads();
#pragma unroll
        for (int kj = 0; kj < 32; ++kj) {
            float4 af0 = *(const float4*)&sA[kj][ty * 8];
            float4 af1 = *(const float4*)&sA[kj][ty * 8 + 4];
            float4 bf0 = *(const float4*)&sB[kj][tx * 8];
            float4 bf1 = *(const float4*)&sB[kj][tx * 8 + 4];
            float am[8] = {af0.x, af0.y, af0.z, af0.w, af1.x, af1.y, af1.z, af1.w};
            float bn[8] = {bf0.x, bf0.y, bf0.z, bf0.w, bf1.x, bf1.y, bf1.z, bf1.w};
#pragma unroll
            for (int i = 0; i < 8; ++i)
#pragma unroll
                for (int j = 0; j < 8; ++j)
                    acc[i][j] = fmaf(am[i], bn[j], acc[i][j]);
        }
        __syncthreads();
    }
#pragma unroll
    for (int i = 0; i < 8; ++i) {
        float* dst = proj + ((size_t)(b0 + ty * 8 + i) * S_ + s) * A_ + a0 + tx * 8;
        *(float4*)(dst) = make_float4(acc[i][0], acc[i][1], acc[i][2], acc[i][3]);
        *(float4*)(dst + 4) = make_float4(acc[i][4], acc[i][5], acc[i][6], acc[i][7]);
    }
}

__global__ void final_loss(const float* __restrict__ nlogp, float* __restrict__ out)
{
    __shared__ float part[C_];
    const int i = threadIdx.x; // 128
    float s = 0.f;
    for (int b = 0; b < B_; ++b) s += nlogp[(size_t)i * B_ + b];
    part[i] = s / (float)B_;
    __syncthreads();
    if (i == 0) {
        float t = 0.f;
        for (int k = 0; k < C_; ++k) t += part[k];
        out[0] = t / (float)B_ / (float)C_;
    }
}

extern "C" void kernel_launch(void* const* d_in, const int* in_sizes, int n_in,
                              void* d_out, int out_size, void* d_ws, size_t ws_size,
                              hipStream_t stream)
{
    (void)in_sizes; (void)n_in; (void)out_size; (void)ws_size;
    const float* x    = (const float*)d_in[0];
    const int*   y    = (const int*)d_in[1];
    const float* eWih = (const float*)d_in[2];
    const float* eWhh = (const float*)d_in[3];
    const float* ebih = (const float*)d_in[4];
    const float* ebhh = (const float*)d_in[5];
    const float* dWih = (const float*)d_in[6];
    const float* dWhh = (const float*)d_in[7];
    const float* dbih = (const float*)d_in[8];
    const float* dbhh = (const float*)d_in[9];
    const float* w1   = (const float*)d_in[10];
    const float* w2   = (const float*)d_in[11];
    const float* v    = (const float*)d_in[12];
    float* out = (float*)d_out;

    float* ws = (float*)d_ws;
    // Region A: encT [128][512][256] = 16,777,216 floats. After proj_gemm,
    // slices t<127 are dead; tail reused (slice 127 at +16,646,144 stays live).
    float* encT    = ws;
    float* W6d     = ws;                    // 983,040
    float* w2pk    = ws + 983040;           // 262,144
    float* hT0     = ws + 1245184;          // 131,072
    float* hT1     = ws + 1376256;          // 131,072
    float* dec_inT = ws + 1507328;          // 32,768
    float* nlogp   = ws + 1540096;          // 32,768
    float* hw2     = ws + 1572864;          // 131,072  (ends 1,703,936 < 16,646,144)
    float* encT127 = ws + 16646144;
    // Region B: proj [B][S][A] = 16,777,216. Before proj written: xT, W6e, h0T.
    float* projB   = ws + 16777216;
    float* xT      = projB;                 // 4,194,304
    float* W6e     = projB + 4194304;       // 983,040
    float* h0T     = projB + 5177344;       // 131,072 (ends 5,308,416)
    // Region C: ws + 33,554,432: biases (16 KB)
    float* bias4e  = ws + 33554432;         // 2048
    float* bias4d  = ws + 33554432 + 2048;  // 2048

    // ---- prep ----
    prep_bias<<<dim3(512), 256, 0, stream>>>(ebih, ebhh, dbih, dbhh,
                                             bias4e, bias4d, h0T);
    transpose_x<<<dim3(512), 256, 0, stream>>>(x, xT);
    prep_w6<<<dim3(3840), 256, 0, stream>>>(eWih, eWhh, W6e);

    // ---- encoder: 128 steps ----
    for (int t = 0; t < S_; ++t) {
        const float* hin = (t == 0) ? h0T : encT + (size_t)(t - 1) * (H_ * B_);
        gru_step<<<dim3(256), 512, 0, stream>>>(
            xT + (size_t)t * (F_ * B_), hin, W6e, bias4e,
            encT + (size_t)t * (H_ * B_));
    }

    // ---- proj ----
    proj_gemm<<<dim3(4, 2, 128), 256, 0, stream>>>(encT, w1, projB);

    // ---- decoder prep (overwrites dead encT slices) ----
    prep_w6<<<dim3(3840), 256, 0, stream>>>(dWih, dWhh, W6d);
    prep_w2pk<<<dim3(1024), 256, 0, stream>>>(w2, w2pk, dec_inT);

    // ---- decoder: 128 steps ----
    float* hb[2] = { hT0, hT1 };
    for (int i = 0; i < C_; ++i) {
        const float* hin = (i == 0) ? encT127 : hb[(i & 1) ^ 1];
        float* hout = hb[i & 1];
        gru_step<<<dim3(256), 512, 0, stream>>>(dec_inT, hin, W6d, bias4d, hout);
        w2_step<<<dim3(256), 512, 0, stream>>>(hout, w2pk, hw2);
        attn_step<<<dim3(256), 256, 0, stream>>>(projB, hw2, v, y, i, x,
                                                 dec_inT, nlogp, out);
    }

    final_loss<<<dim3(1), 128, 0, stream>>>(nlogp, out + (size_t)B_ * C_);
}

// Round 6
// 8132.665 us; speedup vs baseline: 4.9251x; 1.2042x over previous
//
#include <hip/hip_runtime.h>
#include <math.h>

// Problem constants
#define B_ 256
#define S_ 128
#define F_ 128
#define H_ 512
#define A_ 512
#define C_ 128

#define DOT4(va, vb) ((va).x*(vb).x + (va).y*(vb).y + (va).z*(vb).z + (va).w*(vb).w)

// ---------------------------------------------------------------------------
// xT[t][f][b] = x[b][t][f]
// ---------------------------------------------------------------------------
__global__ __launch_bounds__(256)
void transpose_x(const float* __restrict__ x, float* __restrict__ xT)
{
    const int t = blockIdx.x >> 2;
    const int f0 = (blockIdx.x & 3) * 32;
    const int b = threadIdx.x;
#pragma unroll 4
    for (int ff = 0; ff < 32; ++ff) {
        int f = f0 + ff;
        xT[(size_t)t * (F_ * B_) + (size_t)f * B_ + b] =
            x[(size_t)b * (S_ * F_) + (size_t)t * F_ + f];
    }
}

// ---------------------------------------------------------------------------
// W6[up][k][6]: up owns units u0=2up,u0+1. g: r(u0),r(u1),z(u0),z(u1),n(u0),n(u1)
// k<128 -> Wih (K=F), k>=128 -> Whh (K=H)
// ---------------------------------------------------------------------------
__global__ __launch_bounds__(256)
void prep_w6(const float* __restrict__ Wih, const float* __restrict__ Whh,
             float* __restrict__ W6)
{
    int id = blockIdx.x * 256 + threadIdx.x;
    if (id >= 256 * 640 * 6) return;
    int up = id / 3840;
    int rem = id - up * 3840;
    int k = rem / 6, g = rem - k * 6;
    int row = (g >> 1) * H_ + up * 2 + (g & 1);
    float val;
    if (k < F_) val = Wih[(size_t)row * F_ + k];
    else        val = Whh[(size_t)row * H_ + (k - F_)];
    W6[id] = val;
}

// w2q[k4][a] = float4{ w2[a][4k4 .. 4k4+3] }; also zero dec_inT
__global__ __launch_bounds__(256)
void prep_w2q(const float* __restrict__ w2, float4* __restrict__ w2q,
              float* __restrict__ dec_inT)
{
    int id = blockIdx.x * 256 + threadIdx.x;
    if (id < 128 * 512) {
        int k4 = id >> 9, a = id & 511;
        const float* s = w2 + (size_t)a * H_ + k4 * 4;
        w2q[id] = make_float4(s[0], s[1], s[2], s[3]);
    }
    if (id < F_ * B_) dec_inT[id] = 0.f;
}

// bias4[u] = {br, bz, bin, bhn}; zero h0T
__global__ __launch_bounds__(256)
void prep_bias(const float* __restrict__ ebih, const float* __restrict__ ebhh,
               const float* __restrict__ dbih, const float* __restrict__ dbhh,
               float* __restrict__ bias4e, float* __restrict__ bias4d,
               float* __restrict__ h0T)
{
    int id = blockIdx.x * 256 + threadIdx.x;
    if (id < H_ * B_) h0T[id] = 0.f;
    if (id < H_) {
        bias4e[id * 4 + 0] = ebih[id] + ebhh[id];
        bias4e[id * 4 + 1] = ebih[H_ + id] + ebhh[H_ + id];
        bias4e[id * 4 + 2] = ebih[2 * H_ + id];
        bias4e[id * 4 + 3] = ebhh[2 * H_ + id];
        bias4d[id * 4 + 0] = dbih[id] + dbhh[id];
        bias4d[id * 4 + 1] = dbih[H_ + id] + dbhh[H_ + id];
        bias4d[id * 4 + 2] = dbih[2 * H_ + id];
        bias4d[id * 4 + 3] = dbhh[2 * H_ + id];
    }
}

// ---------------------------------------------------------------------------
// accumulate nk k-values from k-major src into acc[0..3] and acc[NH],acc[NH+1]
// ---------------------------------------------------------------------------
template<int NH>
__device__ __forceinline__ void acc_range(const float* __restrict__ src,
                                          const float* __restrict__ W6k,
                                          int nk, int b, float* __restrict__ acc)
{
    float a0[8], a1[8];
#pragma unroll
    for (int j = 0; j < 8; ++j) a0[j] = src[(size_t)j * B_ + b];
    for (int kc = 0; kc < nk; kc += 8) {
        if (kc + 8 < nk) {
#pragma unroll
            for (int j = 0; j < 8; ++j) a1[j] = src[(size_t)(kc + 8 + j) * B_ + b];
        }
        const float* Wr = W6k + (size_t)kc * 6;
#pragma unroll
        for (int j = 0; j < 8; ++j) {
            float av = a0[j];
            acc[0]      = fmaf(av, Wr[j * 6 + 0], acc[0]);
            acc[1]      = fmaf(av, Wr[j * 6 + 1], acc[1]);
            acc[2]      = fmaf(av, Wr[j * 6 + 2], acc[2]);
            acc[3]      = fmaf(av, Wr[j * 6 + 3], acc[3]);
            acc[NH]     = fmaf(av, Wr[j * 6 + 4], acc[NH]);
            acc[NH + 1] = fmaf(av, Wr[j * 6 + 5], acc[NH + 1]);
        }
#pragma unroll
        for (int j = 0; j < 8; ++j) a0[j] = a1[j];
    }
}

// ---------------------------------------------------------------------------
// One GRU step. 256 blocks (unit-pair each), 512 threads = 8 waves.
// If hB != nullptr, also write b-major copy of h_new.
// ---------------------------------------------------------------------------
__global__ __launch_bounds__(512)
void gru_step(const float* __restrict__ inT,    // [F_][B_] (k-major)
              const float* __restrict__ hinT,   // [H_][B_]
              const float* __restrict__ W6,     // [256][640][6]
              const float* __restrict__ bias4,  // [512][4]
              float* __restrict__ houtT,        // [H_][B_]
              float* __restrict__ hB)           // [B_][H_] or nullptr
{
    __shared__ float accL[256][6];
    const int tid = threadIdx.x;
    const int lane = tid & 63;
    const int w = tid >> 6;
    const int bg = w & 3;
    const int kw = w >> 2;
    const int b = bg * 64 + lane;
    const int up = blockIdx.x;
    const float* Wb = W6 + (size_t)up * (640 * 6);

    float acc[8];
#pragma unroll
    for (int g = 0; g < 8; ++g) acc[g] = 0.f;

    if (kw == 0) {
        acc_range<4>(inT, Wb, F_, b, acc);                       // x: k 0..127
        acc_range<6>(hinT, Wb + F_ * 6, 192, b, acc);            // h: k 0..191
    } else {
        acc_range<6>(hinT + (size_t)192 * B_, Wb + 320 * 6, 320, b, acc); // h: 192..511
    }

    if (kw == 1) {
        const int li = tid & 255;
        accL[li][0] = acc[0]; accL[li][1] = acc[1];
        accL[li][2] = acc[2]; accL[li][3] = acc[3];
        accL[li][4] = acc[6]; accL[li][5] = acc[7];
    }
    __syncthreads();
    if (kw == 0) {
        const int u0 = up * 2, u1 = u0 + 1;
        float4 bb0 = *(const float4*)(bias4 + u0 * 4);
        float4 bb1 = *(const float4*)(bias4 + u1 * 4);
        float rr0 = 1.f / (1.f + expf(-(acc[0] + accL[tid][0] + bb0.x)));
        float rr1 = 1.f / (1.f + expf(-(acc[1] + accL[tid][1] + bb1.x)));
        float zz0 = 1.f / (1.f + expf(-(acc[2] + accL[tid][2] + bb0.y)));
        float zz1 = 1.f / (1.f + expf(-(acc[3] + accL[tid][3] + bb1.y)));
        float hn0 = acc[6] + accL[tid][4] + bb0.w;
        float hn1 = acc[7] + accL[tid][5] + bb1.w;
        float nn0 = tanhf(acc[4] + bb0.z + rr0 * hn0);
        float nn1 = tanhf(acc[5] + bb1.z + rr1 * hn1);
        float ho0 = hinT[(size_t)u0 * B_ + b];
        float ho1 = hinT[(size_t)u1 * B_ + b];
        float h0v = (1.f - zz0) * nn0 + zz0 * ho0;
        float h1v = (1.f - zz1) * nn1 + zz1 * ho1;
        houtT[(size_t)u0 * B_ + b] = h0v;
        houtT[(size_t)u1 * B_ + b] = h1v;
        if (hB) {
            hB[(size_t)b * H_ + u0] = h0v;
            hB[(size_t)b * H_ + u1] = h1v;
        }
    }
}

// ---------------------------------------------------------------------------
// Fused: hw2 = h_new[b] @ w2^T (in LDS) -> scores -> softmax -> argmax ->
// loss -> gather next dec input. Block = batch b, 512 threads (8 waves).
// ---------------------------------------------------------------------------
__global__ __launch_bounds__(512)
void w2attn_step(const float* __restrict__ hB,    // [B_][H_]
                 const float4* __restrict__ w2q,  // [128 k4][512 a]
                 const float* __restrict__ v, const int* __restrict__ y,
                 int step, const float* __restrict__ x,
                 const float* __restrict__ proj,  // [b][s][a]
                 float* __restrict__ dec_inT,     // [F_][B_]
                 float* __restrict__ nlogp, float* __restrict__ preds_out)
{
    const int b = blockIdx.x;
    const int tid = threadIdx.x;
    __shared__ float sh[512];
    __shared__ float sq[512];
    __shared__ float sScore[S_], sProb[S_];
    __shared__ int sPred;

    sh[tid] = hB[(size_t)b * H_ + tid];
    __syncthreads();

    // ---- hw2[b][a], a = tid ----
    {
        float acc = 0.f;
        const float4* wp = w2q + tid;
#pragma unroll 8
        for (int k4 = 0; k4 < 128; ++k4) {
            float4 hv = *(const float4*)&sh[k4 * 4];
            float4 wv4 = wp[(size_t)k4 * 512];
            acc += DOT4(hv, wv4);
        }
        sq[tid] = acc;
    }
    __syncthreads();

    // ---- scores: wave wv handles s = si*8+wv; lane owns 8-wide A slice ----
    const int wv = tid >> 6, ln = tid & 63;
    float4 q0 = *(const float4*)&sq[ln * 8];
    float4 q1 = *(const float4*)&sq[ln * 8 + 4];
    float4 v0r = *(const float4*)(v + ln * 8);
    float4 v1r = *(const float4*)(v + ln * 8 + 4);
    const float* epb = proj + (size_t)b * (S_ * A_);
    for (int si = 0; si < 16; ++si) {
        int s = si * 8 + wv;
        const float* row = epb + (size_t)s * A_ + ln * 8;
        float4 p0 = *(const float4*)(row);
        float4 p1 = *(const float4*)(row + 4);
        float acc = fmaxf(p0.x + q0.x, 0.f) * v0r.x
                  + fmaxf(p0.y + q0.y, 0.f) * v0r.y
                  + fmaxf(p0.z + q0.z, 0.f) * v0r.z
                  + fmaxf(p0.w + q0.w, 0.f) * v0r.w
                  + fmaxf(p1.x + q1.x, 0.f) * v1r.x
                  + fmaxf(p1.y + q1.y, 0.f) * v1r.y
                  + fmaxf(p1.z + q1.z, 0.f) * v1r.z
                  + fmaxf(p1.w + q1.w, 0.f) * v1r.w;
#pragma unroll
        for (int off = 32; off; off >>= 1) acc += __shfl_down(acc, off);
        if (ln == 0) sScore[s] = acc;
    }
    __syncthreads();

    // ---- softmax / log_softmax / argmax / loss (one wave) ----
    if (tid < 64) {
        float s0v = sScore[tid], s1v = sScore[tid + 64];
        float m = fmaxf(s0v, s1v);
#pragma unroll
        for (int off = 32; off; off >>= 1) m = fmaxf(m, __shfl_xor(m, off));
        float e0 = expf(s0v - m), e1 = expf(s1v - m);
        float se = e0 + e1;
#pragma unroll
        for (int off = 32; off; off >>= 1) se += __shfl_xor(se, off);
        float p0 = e0 / se, p1 = e1 / se;
        sProb[tid] = p0; sProb[tid + 64] = p1;
        float pm = fmaxf(p0, p1);
#pragma unroll
        for (int off = 32; off; off >>= 1) pm = fmaxf(pm, __shfl_xor(pm, off));
        float t0 = expf(p0 - pm), t1 = expf(p1 - pm);
        float T = t0 + t1;
#pragma unroll
        for (int off = 32; off; off >>= 1) T += __shfl_xor(T, off);
        float bv = p0; int bi2 = tid;
        if (p1 > bv) { bv = p1; bi2 = tid + 64; }
#pragma unroll
        for (int off = 32; off; off >>= 1) {
            float ov = __shfl_xor(bv, off);
            int oi = __shfl_xor(bi2, off);
            if (ov > bv || (ov == bv && oi < bi2)) { bv = ov; bi2 = oi; }
        }
        if (tid == 0) {
            sPred = bi2;
            int yy = y[(size_t)b * C_ + step];
            float py = sProb[yy];
            nlogp[(size_t)step * B_ + b] = -(py - pm - logf(T));
            preds_out[(size_t)b * C_ + step] = (float)bi2;
        }
    }
    __syncthreads();

    // ---- gather next decoder input (transposed) ----
    const int pred = sPred;
    if (tid < F_) {
        dec_inT[(size_t)tid * B_ + b] = x[((size_t)b * S_ + pred) * F_ + tid];
    }
}

// ---------------------------------------------------------------------------
// proj[b][s][a] = sum_j encT[s][j][b] * w1[a][j]   (TN GEMM, 128x128 tiles)
// ---------------------------------------------------------------------------
__global__ __launch_bounds__(256)
void proj_gemm(const float* __restrict__ encT, const float* __restrict__ w1,
               float* __restrict__ proj)
{
    __shared__ float sA[32][128];
    __shared__ float sB[32][128];
    const int tid = threadIdx.x;
    const int s = blockIdx.z;
    const int b0 = blockIdx.y * 128;
    const int a0 = blockIdx.x * 128;
    const int tx = tid & 15, ty = tid >> 4;

    float acc[8][8];
#pragma unroll
    for (int i = 0; i < 8; ++i)
#pragma unroll
        for (int j = 0; j < 8; ++j) acc[i][j] = 0.f;

    const float* Abase = encT + (size_t)s * (H_ * B_) + b0;
    for (int kc = 0; kc < H_; kc += 32) {
#pragma unroll
        for (int p = 0; p < 16; ++p) {
            int idx = tid + p * 256;
            int kj = idx >> 7, bb = idx & 127;
            sA[kj][bb] = Abase[(size_t)(kc + kj) * B_ + bb];
        }
#pragma unroll
        for (int p = 0; p < 16; ++p) {
            int idx = tid + p * 256;
            int aa = idx >> 5, kj = idx & 31;
            sB[kj][aa] = w1[(size_t)(a0 + aa) * H_ + kc + kj];
        }
        __syncthreads();
#pragma unroll
        for (int kj = 0; kj < 32; ++kj) {
            float4 af0 = *(const float4*)&sA[kj][ty * 8];
            float4 af1 = *(const float4*)&sA[kj][ty * 8 + 4];
            float4 bf0 = *(const float4*)&sB[kj][tx * 8];
            float4 bf1 = *(const float4*)&sB[kj][tx * 8 + 4];
            float am[8] = {af0.x, af0.y, af0.z, af0.w, af1.x, af1.y, af1.z, af1.w};
            float bn[8] = {bf0.x, bf0.y, bf0.z, bf0.w, bf1.x, bf1.y, bf1.z, bf1.w};
#pragma unroll
            for (int i = 0; i < 8; ++i)
#pragma unroll
                for (int j = 0; j < 8; ++j)
                    acc[i][j] = fmaf(am[i], bn[j], acc[i][j]);
        }
        __syncthreads();
    }
#pragma unroll
    for (int i = 0; i < 8; ++i) {
        float* dst = proj + ((size_t)(b0 + ty * 8 + i) * S_ + s) * A_ + a0 + tx * 8;
        *(float4*)(dst) = make_float4(acc[i][0], acc[i][1], acc[i][2], acc[i][3]);
        *(float4*)(dst + 4) = make_float4(acc[i][4], acc[i][5], acc[i][6], acc[i][7]);
    }
}

__global__ void final_loss(const float* __restrict__ nlogp, float* __restrict__ out)
{
    __shared__ float part[C_];
    const int i = threadIdx.x; // 128
    float s = 0.f;
    for (int b = 0; b < B_; ++b) s += nlogp[(size_t)i * B_ + b];
    part[i] = s / (float)B_;
    __syncthreads();
    if (i == 0) {
        float t = 0.f;
        for (int k = 0; k < C_; ++k) t += part[k];
        out[0] = t / (float)B_ / (float)C_;
    }
}

extern "C" void kernel_launch(void* const* d_in, const int* in_sizes, int n_in,
                              void* d_out, int out_size, void* d_ws, size_t ws_size,
                              hipStream_t stream)
{
    (void)in_sizes; (void)n_in; (void)out_size; (void)ws_size;
    const float* x    = (const float*)d_in[0];
    const int*   y    = (const int*)d_in[1];
    const float* eWih = (const float*)d_in[2];
    const float* eWhh = (const float*)d_in[3];
    const float* ebih = (const float*)d_in[4];
    const float* ebhh = (const float*)d_in[5];
    const float* dWih = (const float*)d_in[6];
    const float* dWhh = (const float*)d_in[7];
    const float* dbih = (const float*)d_in[8];
    const float* dbhh = (const float*)d_in[9];
    const float* w1   = (const float*)d_in[10];
    const float* w2   = (const float*)d_in[11];
    const float* v    = (const float*)d_in[12];
    float* out = (float*)d_out;

    float* ws = (float*)d_ws;
    // Region A: encT [128][512][256] = 16,777,216 floats. After proj_gemm,
    // slices t<127 are dead; reused for decoder data (slice 127 stays live).
    float* encT    = ws;
    float* W6d     = ws;                    // 983,040
    float* w2qf    = ws + 983040;           // 262,144 (float4 view below)
    float* hT0     = ws + 1245184;          // 131,072
    float* hT1     = ws + 1376256;          // 131,072
    float* dec_inT = ws + 1507328;          // 32,768
    float* nlogp   = ws + 1540096;          // 32,768
    float* hB      = ws + 1572864;          // 131,072 (ends 1,703,936 < 16,646,144)
    float* encT127 = ws + 16646144;
    // Region B: proj. Before proj written: xT, W6e, h0T.
    float* projB   = ws + 16777216;
    float* xT      = projB;                 // 4,194,304
    float* W6e     = projB + 4194304;       // 983,040
    float* h0T     = projB + 5177344;       // 131,072
    // Region C
    float* bias4e  = ws + 33554432;
    float* bias4d  = ws + 33554432 + 2048;

    // ---- prep ----
    prep_bias<<<dim3(512), 256, 0, stream>>>(ebih, ebhh, dbih, dbhh,
                                             bias4e, bias4d, h0T);
    transpose_x<<<dim3(512), 256, 0, stream>>>(x, xT);
    prep_w6<<<dim3(3840), 256, 0, stream>>>(eWih, eWhh, W6e);

    // ---- encoder: 128 steps ----
    for (int t = 0; t < S_; ++t) {
        const float* hin = (t == 0) ? h0T : encT + (size_t)(t - 1) * (H_ * B_);
        gru_step<<<dim3(256), 512, 0, stream>>>(
            xT + (size_t)t * (F_ * B_), hin, W6e, bias4e,
            encT + (size_t)t * (H_ * B_), (float*)nullptr);
    }

    // ---- proj ----
    proj_gemm<<<dim3(4, 2, 128), 256, 0, stream>>>(encT, w1, projB);

    // ---- decoder prep (into dead encT slices) ----
    prep_w6<<<dim3(3840), 256, 0, stream>>>(dWih, dWhh, W6d);
    prep_w2q<<<dim3(256), 256, 0, stream>>>(w2, (float4*)w2qf, dec_inT);

    // ---- decoder: 128 steps x 2 kernels ----
    float* hb[2] = { hT0, hT1 };
    for (int i = 0; i < C_; ++i) {
        const float* hin = (i == 0) ? encT127 : hb[(i & 1) ^ 1];
        float* hout = hb[i & 1];
        gru_step<<<dim3(256), 512, 0, stream>>>(dec_inT, hin, W6d, bias4d,
                                                hout, hB);
        w2attn_step<<<dim3(256), 512, 0, stream>>>(hB, (const float4*)w2qf, v, y,
                                                   i, x, projB, dec_inT,
                                                   nlogp, out);
    }

    final_loss<<<dim3(1), 128, 0, stream>>>(nlogp, out + (size_t)B_ * C_);
}